// Round 9
// baseline (149.601 us; speedup 1.0000x reference)
//
#include <hip/hip_runtime.h>
#include <math.h>

// FourierFlow: out[t,n,i] = sum_j expm((M*omega + M0)*t)[i,j] * x[n,j]
// Inputs: x (16384,16) f32 | t (512,) f32 | omega (1,) f32 | M (16,16) f32 | M0 (16,16) f32
// Output: (512, 16384, 16) f32 = 536.9 MB -> write-BW bound (~81 us floor at 6.6 TB/s).
//
// Round 9 = R6 store structure + lane-distinct x loads.
// Each lane loads ONE 16B chunk (wave load = 1 KB contiguous, fill-like),
// quad exchanges chunks via __shfl_xor (DPP quad-perm). E fragment is loaded
// pre-permuted so all register indexing stays compile-time.

#define MDIM 16
#define MELEMS 256
#define BLOCKS_PER_T 4
#define ROWS_PER_BLOCK 4096   // N / BLOCKS_PER_T
#define KSTEPS 64             // ROWS_PER_BLOCK / 64 rows-per-step

// ---------------- Kernel 1: batched 16x16 matrix exponential ----------------
__global__ __launch_bounds__(256) void expm_kernel(
    const float* __restrict__ t,
    const float* __restrict__ omega,
    const float* __restrict__ M,
    const float* __restrict__ M0,
    float* __restrict__ E /* (T,16,16) */) {
  __shared__ float A[MELEMS];
  __shared__ float T[MELEMS];
  __shared__ float rowsum[MDIM];

  const int bt  = blockIdx.x;
  const int tid = threadIdx.x;
  const int i = tid >> 4;
  const int j = tid & 15;

  const float tv = t[bt];
  const float om = omega[0];
  const float a = (M[tid] * om + M0[tid]) * tv;

  // parallel inf-norm: row-sum via 16-lane shuffle butterfly, then max over rows
  float rs = fabsf(a);
  rs += __shfl_xor(rs, 1);
  rs += __shfl_xor(rs, 2);
  rs += __shfl_xor(rs, 4);
  rs += __shfl_xor(rs, 8);
  if (j == 0) rowsum[i] = rs;
  __syncthreads();
  float nrm = 0.f;
#pragma unroll
  for (int r = 0; r < MDIM; ++r) nrm = fmaxf(nrm, rowsum[r]);
  // scaling exponent: nrm / 2^s <= 0.5
  int s = (nrm > 1e-30f) ? (ilogbf(nrm) + 2) : 0;
  if (s < 0) s = 0;

  const float b = ldexpf(a, -s);
  const float ident = (i == j) ? 1.0f : 0.0f;
  A[tid] = b;
  T[tid] = ident;
  __syncthreads();

  // Horner-Taylor: for k = K..1: T = I + (B @ T) / k
  for (int k = 8; k >= 1; --k) {
    float acc = 0.f;
#pragma unroll
    for (int c = 0; c < MDIM; ++c) acc += A[i * MDIM + c] * T[c * MDIM + j];
    __syncthreads();
    T[tid] = ident + acc * (1.0f / (float)k);
    __syncthreads();
  }

  // square s times
  for (int k = 0; k < s; ++k) {
    float acc = 0.f;
#pragma unroll
    for (int c = 0; c < MDIM; ++c) acc += T[i * MDIM + c] * T[c * MDIM + j];
    __syncthreads();
    T[tid] = acc;
    __syncthreads();
  }

  E[(size_t)bt * MELEMS + tid] = T[tid];
}

__device__ __forceinline__ float4 shflx4(float4 v, int m) {
  float4 r;
  r.x = __shfl_xor(v.x, m);
  r.y = __shfl_xor(v.y, m);
  r.z = __shfl_xor(v.z, m);
  r.w = __shfl_xor(v.w, m);
  return r;
}

// ---------------- Kernel 2: out[t,n,:] = E[t] @ x[n,:] ----------------
// 2048 blocks = 512 t x 4 row-quarters, 256 threads. Quad nl handles row
// base+nl+64k; lane (nl,i4) computes output dims [4*i4, 4*i4+4).
// Loads: lane reads ONLY chunk i4 of its row -> wave load instr = 64 lanes x
// 16B consecutive = 1 KB contiguous (fill-like). Quad then exchanges chunks
// with 3 shfl_xor (DPP). E fragment loaded pre-permuted: e[r*4+m] = chunk
// (i4^m) of E row (i4*4+r), so DOT indices are all compile-time.
// Stores: identical to R6 -- contiguous 1 KB wave-stores, loads for step k+1
// issued BEFORE the store of step k (vmcnt never drains HBM stores).
__global__ __launch_bounds__(256, 4) void apply_kernel(
    const float* __restrict__ E,  /* (T,16,16) */
    const float* __restrict__ x,  /* (N,16)    */
    float* __restrict__ out,      /* (T,N,16)  */
    int N) {
  const int blk = blockIdx.x;
  const int t   = blk >> 2;                    // 4 blocks per t
  const int tid = threadIdx.x;
  const int i4 = tid & 3;
  const int nl = tid >> 2;

  // pre-permuted E fragment -> 16 float4 registers (once per block)
  float4 e[16];
  const float4* __restrict__ Er = (const float4*)(E + (size_t)t * MELEMS);
#pragma unroll
  for (int r = 0; r < 4; ++r)
#pragma unroll
    for (int m = 0; m < 4; ++m)
      e[r * 4 + m] = Er[(i4 * 4 + r) * 4 + (i4 ^ m)];

  const size_t base = (size_t)(blk & 3) * ROWS_PER_BLOCK;  // row base in t-slice
  const float4* __restrict__ xin = (const float4*)x;
  float4* __restrict__ op = (float4*)(out + ((size_t)t * N + base) * MDIM);

  float4 xa, xb;  // own 16B chunk of current / next row

#define LOADX1(d, k) do {                                     \
    d = xin[(base + nl + (size_t)(k) * 64) * 4 + i4];         \
  } while (0)

  // expand own chunk to the full row via quad shuffles, then dot.
#define DOTX(o, xo) do {                                                   \
    const float4 xv0 = (xo);                                               \
    const float4 xv1 = shflx4((xo), 1);                                    \
    const float4 xv2 = shflx4((xo), 2);                                    \
    const float4 xv3 = shflx4((xo), 3);                                    \
    _Pragma("unroll")                                                      \
    for (int r = 0; r < 4; ++r) {                                          \
      const float4 ea = e[r * 4 + 0], eb = e[r * 4 + 1];                   \
      const float4 ec = e[r * 4 + 2], ed = e[r * 4 + 3];                   \
      o[r] = ea.x * xv0.x + ea.y * xv0.y + ea.z * xv0.z + ea.w * xv0.w     \
           + eb.x * xv1.x + eb.y * xv1.y + eb.z * xv1.z + eb.w * xv1.w     \
           + ec.x * xv2.x + ec.y * xv2.y + ec.z * xv2.z + ec.w * xv2.w     \
           + ed.x * xv3.x + ed.y * xv3.y + ed.z * xv3.z + ed.w * xv3.w;    \
    }                                                                      \
  } while (0)

  LOADX1(xa, 0);
#pragma unroll 4
  for (int k = 0; k < KSTEPS; k += 2) {
    float o[4];
    // step k (in xa): prefetch k+1 into xb BEFORE storing step k
    LOADX1(xb, k + 1);
    DOTX(o, xa);
    op[k * 256 + tid] = make_float4(o[0], o[1], o[2], o[3]);
    // step k+1 (in xb): prefetch k+2 into xa BEFORE storing step k+1
    if (k + 2 < KSTEPS) LOADX1(xa, k + 2);
    DOTX(o, xb);
    op[(k + 1) * 256 + tid] = make_float4(o[0], o[1], o[2], o[3]);
  }
#undef LOADX1
#undef DOTX
}

extern "C" void kernel_launch(void* const* d_in, const int* in_sizes, int n_in,
                              void* d_out, int out_size, void* d_ws, size_t ws_size,
                              hipStream_t stream) {
  const float* x     = (const float*)d_in[0];
  const float* t     = (const float*)d_in[1];
  const float* omega = (const float*)d_in[2];
  const float* M     = (const float*)d_in[3];
  const float* M0    = (const float*)d_in[4];
  float* out = (float*)d_out;

  const int N = in_sizes[0] / MDIM;   // 16384
  const int T = in_sizes[1];          // 512

  float* E = (float*)d_ws;            // T*256 floats = 512 KB

  expm_kernel<<<T, 256, 0, stream>>>(t, omega, M, M0, E);

  apply_kernel<<<T * BLOCKS_PER_T, 256, 0, stream>>>(E, x, out, N);
}

// Round 10
// 115.841 us; speedup vs baseline: 1.2914x; 1.2914x over previous
//
#include <hip/hip_runtime.h>
#include <math.h>

// FourierFlow: out[t,n,i] = sum_j expm((M*omega + M0)*t)[i,j] * x[n,j]
// Inputs: x (16384,16) f32 | t (512,) f32 | omega (1,) f32 | M (16,16) f32 | M0 (16,16) f32
// Output: (512, 16384, 16) f32 = 536.9 MB -> write-BW bound (~81 us floor at 6.6 TB/s).
//
// Round 10: store-pure inner loop. Block stages 512 x-rows (40KB, 80B-padded)
// + 16 E matrices (20KB, 80B-padded rows) in LDS once; after one barrier the
// 16-t x 8-step loop issues ONLY contiguous 1KB wave-stores on the vector
// pipe (all reads are ds_read_b128 -> lgkmcnt, which never forces store
// completion). This removes the per-iteration vmcnt store-drains that
// distinguish us from the 6.6 TB/s fill kernel.

#define MDIM 16
#define MELEMS 256
#define RROWS 512          // x rows per block
#define TC 16              // t values per block
#define XPAD 20            // floats per x row in LDS (80 B, 16B-aligned, 2-way banks)
#define EPAD 20            // floats per E row in LDS
#define ESTRIDE (16 * EPAD) // floats per staged E matrix

// ---------------- Kernel 1: batched 16x16 matrix exponential ----------------
__global__ __launch_bounds__(256) void expm_kernel(
    const float* __restrict__ t,
    const float* __restrict__ omega,
    const float* __restrict__ M,
    const float* __restrict__ M0,
    float* __restrict__ E /* (T,16,16) */) {
  __shared__ float A[MELEMS];
  __shared__ float T[MELEMS];
  __shared__ float rowsum[MDIM];

  const int bt  = blockIdx.x;
  const int tid = threadIdx.x;
  const int i = tid >> 4;
  const int j = tid & 15;

  const float tv = t[bt];
  const float om = omega[0];
  const float a = (M[tid] * om + M0[tid]) * tv;

  // parallel inf-norm: row-sum via 16-lane shuffle butterfly, then max over rows
  float rs = fabsf(a);
  rs += __shfl_xor(rs, 1);
  rs += __shfl_xor(rs, 2);
  rs += __shfl_xor(rs, 4);
  rs += __shfl_xor(rs, 8);
  if (j == 0) rowsum[i] = rs;
  __syncthreads();
  float nrm = 0.f;
#pragma unroll
  for (int r = 0; r < MDIM; ++r) nrm = fmaxf(nrm, rowsum[r]);
  // scaling exponent: nrm / 2^s <= 0.5
  int s = (nrm > 1e-30f) ? (ilogbf(nrm) + 2) : 0;
  if (s < 0) s = 0;

  const float b = ldexpf(a, -s);
  const float ident = (i == j) ? 1.0f : 0.0f;
  A[tid] = b;
  T[tid] = ident;
  __syncthreads();

  // Horner-Taylor: for k = K..1: T = I + (B @ T) / k
  for (int k = 8; k >= 1; --k) {
    float acc = 0.f;
#pragma unroll
    for (int c = 0; c < MDIM; ++c) acc += A[i * MDIM + c] * T[c * MDIM + j];
    __syncthreads();
    T[tid] = ident + acc * (1.0f / (float)k);
    __syncthreads();
  }

  // square s times
  for (int k = 0; k < s; ++k) {
    float acc = 0.f;
#pragma unroll
    for (int c = 0; c < MDIM; ++c) acc += T[i * MDIM + c] * T[c * MDIM + j];
    __syncthreads();
    T[tid] = acc;
    __syncthreads();
  }

  E[(size_t)bt * MELEMS + tid] = T[tid];
}

// ---------------- Kernel 2: out[t,n,:] = E[t] @ x[n,:] ----------------
// grid = (T/TC) * (N/RROWS) = 32*32 = 1024 blocks, 256 threads (4 waves).
// Lane (nl = tid>>2, i4 = tid&3): row group nl, output dims [4*i4, 4*i4+4).
// Per t: E fragment from LDS (16 b128, 4-addr broadcast, 2-way banks), then
// 8 steps of {4 b128 x-row reads (16-addr broadcast, 2-way banks), 16 FMAs x4,
// one contiguous 1 KB wave-store}. Zero global loads in the loop.
__global__ __launch_bounds__(256) void apply_kernel(
    const float* __restrict__ E,  /* (T,16,16) */
    const float* __restrict__ x,  /* (N,16)    */
    float* __restrict__ out,      /* (T,N,16)  */
    int N) {
  __shared__ __align__(16) float XS[RROWS * XPAD]; // 40 KB
  __shared__ __align__(16) float ES[TC * ESTRIDE]; // 20 KB

  const int blk = blockIdx.x;
  const int rq  = blk & 31;   // N / RROWS = 32 row groups
  const int tq  = blk >> 5;   // T / TC    = 32 t groups
  const int tid = threadIdx.x;
  const int i4 = tid & 3;
  const int nl = tid >> 2;

  const size_t base = (size_t)rq * RROWS;

  // ---- stage x rows (32 KB raw) and E t-tile (16 KB raw) into padded LDS ----
  {
    const float4* __restrict__ xg = (const float4*)(x + base * MDIM);
#pragma unroll
    for (int i = 0; i < 8; ++i) {
      const int g = tid + i * 256;          // float4 idx < 2048
      const float4 v = xg[g];
      const int row = g >> 2, ch = g & 3;
      *(float4*)(&XS[row * XPAD + ch * 4]) = v;
    }
    const float4* __restrict__ eg = (const float4*)(E + (size_t)(tq * TC) * MELEMS);
#pragma unroll
    for (int i = 0; i < 4; ++i) {
      const int g = tid + i * 256;          // float4 idx < 1024
      const float4 v = eg[g];
      const int tl = g >> 6, rem = g & 63;
      const int row = rem >> 2, ch = rem & 3;
      *(float4*)(&ES[tl * ESTRIDE + row * EPAD + ch * 4]) = v;
    }
  }
  __syncthreads();

  const size_t slice = (size_t)N * MDIM;

  for (int tt = 0; tt < TC; ++tt) {
    // E fragment rows [4*i4, 4*i4+4) -> 16 float4 regs
    float4 e[16];
#pragma unroll
    for (int r = 0; r < 4; ++r)
#pragma unroll
      for (int q = 0; q < 4; ++q)
        e[r * 4 + q] =
            *(const float4*)(&ES[tt * ESTRIDE + (i4 * 4 + r) * EPAD + q * 4]);

    float4* __restrict__ op =
        (float4*)(out + (size_t)(tq * TC + tt) * slice + base * MDIM);

#pragma unroll
    for (int k = 0; k < RROWS / 64; ++k) {
      const float* __restrict__ xr = &XS[(nl + k * 64) * XPAD];
      const float4 x0 = *(const float4*)(xr);
      const float4 x1 = *(const float4*)(xr + 4);
      const float4 x2 = *(const float4*)(xr + 8);
      const float4 x3 = *(const float4*)(xr + 12);

      float o[4];
#pragma unroll
      for (int r = 0; r < 4; ++r) {
        const float4 ea = e[r * 4 + 0], eb = e[r * 4 + 1];
        const float4 ec = e[r * 4 + 2], ed = e[r * 4 + 3];
        o[r] = ea.x * x0.x + ea.y * x0.y + ea.z * x0.z + ea.w * x0.w
             + eb.x * x1.x + eb.y * x1.y + eb.z * x1.z + eb.w * x1.w
             + ec.x * x2.x + ec.y * x2.y + ec.z * x2.z + ec.w * x2.w
             + ed.x * x3.x + ed.y * x3.y + ed.z * x3.z + ed.w * x3.w;
      }
      op[k * 256 + tid] = make_float4(o[0], o[1], o[2], o[3]);
    }
  }
}

extern "C" void kernel_launch(void* const* d_in, const int* in_sizes, int n_in,
                              void* d_out, int out_size, void* d_ws, size_t ws_size,
                              hipStream_t stream) {
  const float* x     = (const float*)d_in[0];
  const float* t     = (const float*)d_in[1];
  const float* omega = (const float*)d_in[2];
  const float* M     = (const float*)d_in[3];
  const float* M0    = (const float*)d_in[4];
  float* out = (float*)d_out;

  const int N = in_sizes[0] / MDIM;   // 16384
  const int T = in_sizes[1];          // 512

  float* E = (float*)d_ws;            // T*256 floats = 512 KB

  expm_kernel<<<T, 256, 0, stream>>>(t, omega, M, M0, E);

  const int grid = (T / TC) * (N / RROWS);  // 32 * 32 = 1024
  apply_kernel<<<grid, 256, 0, stream>>>(E, x, out, N);
}